// Round 1
// baseline (371.044 us; speedup 1.0000x reference)
//
#include <hip/hip_runtime.h>

#define NBINS 4096
#define CAP   16384
#define BPB   128   // blocks per batch for streaming kernels
#define TPB   256
#define NB    8     // batch

static __device__ __forceinline__ int bucketOf(float v) {
    int b = (int)(v * (float)NBINS);
    if (b < 0) b = 0;
    if (b > NBINS - 1) b = NBINS - 1;
    return b;
}

// ---------------- pass 1: mask count, SSE, histograms ----------------
__global__ __launch_bounds__(TPB) void k_pass1(const float* __restrict__ pred,
                                               const float* __restrict__ targ,
                                               int nvec,
                                               unsigned* __restrict__ hist,
                                               double* __restrict__ sse,
                                               unsigned* __restrict__ nvalid)
{
    __shared__ unsigned h[2 * NBINS];
    for (int i = threadIdx.x; i < 2 * NBINS; i += blockDim.x) h[i] = 0u;
    __syncthreads();

    const int b = blockIdx.y;
    const float4* p4 = (const float4*)pred + (size_t)b * nvec;
    const float4* t4 = (const float4*)targ + (size_t)b * nvec;

    float    lsse = 0.f;
    unsigned lnv = 0, lnp = 0;

    for (int i = blockIdx.x * blockDim.x + threadIdx.x; i < nvec;
         i += gridDim.x * blockDim.x) {
        float4 t = t4[i];
        float4 p = p4[i];
        float tv[4] = {t.x, t.y, t.z, t.w};
        float pv[4] = {p.x, p.y, p.z, p.w};
#pragma unroll
        for (int j = 0; j < 4; ++j) {
            float tt = tv[j], pp = pv[j];
            if (tt > 0.01f) {
                float d = pp - tt;
                lsse += d * d;
                lnv++;
                atomicAdd(&h[bucketOf(tt)], 1u);
                if (pp > 0.f) {
                    lnp++;
                    atomicAdd(&h[NBINS + bucketOf(pp)], 1u);
                }
            }
        }
    }
    __syncthreads();

    unsigned* gh = hist + (size_t)b * 2 * NBINS;
    for (int i = threadIdx.x; i < 2 * NBINS; i += blockDim.x) {
        unsigned v = h[i];
        if (v) atomicAdd(&gh[i], v);
    }

    // wave reduce scalars
    for (int off = 32; off; off >>= 1) {
        lsse += __shfl_down(lsse, off);
        lnv  += __shfl_down(lnv, off);
        lnp  += __shfl_down(lnp, off);
    }
    if ((threadIdx.x & 63) == 0) {
        atomicAdd(&sse[b], (double)lsse);
        atomicAdd(&nvalid[2 * b + 0], lnv);
        atomicAdd(&nvalid[2 * b + 1], lnp);
    }
}

// ---------------- pass 2: scan histogram, locate rank buckets ----------------
// binfo per (b,tensor), 8 u32: [0]=b_lo [1]=b_hi [2]=cum_below [3]=k
// [4]=frac(float bits) [5]=nv
__global__ __launch_bounds__(256) void k_scan(const unsigned* __restrict__ hist,
                                              const unsigned* __restrict__ nvalid,
                                              unsigned* __restrict__ binfo)
{
    const int bt = blockIdx.x;  // 0..15
    const unsigned nv = nvalid[bt];
    unsigned* bi = binfo + bt * 8;
    const unsigned* h = hist + (size_t)bt * NBINS;

    __shared__ unsigned partial[256];
    __shared__ unsigned sk;
    __shared__ unsigned sr2;

    if (threadIdx.x == 0) {
        bi[5] = nv;
        if (nv == 0) {
            bi[0] = 0xFFFFFFFFu;
            bi[1] = 0xFFFFFFFFu;
            bi[2] = 0;
            bi[3] = 0;
            bi[4] = __float_as_uint(0.0f);
        } else {
            double pos   = 0.9 * (double)(nv - 1);
            unsigned k   = (unsigned)pos;
            double frac  = pos - (double)k;
            bi[3] = k;
            bi[4] = __float_as_uint((float)frac);
            sk = k;
            sr2 = (k + 2 <= nv) ? (k + 2) : (k + 1);
        }
    }
    __syncthreads();
    if (nv == 0) return;

    const unsigned k = sk, r1 = sk + 1, r2 = sr2;

    // each thread owns 16 bins
    const int lo = threadIdx.x * (NBINS / 256);
    unsigned local[NBINS / 256];
    unsigned ls = 0;
#pragma unroll
    for (int j = 0; j < NBINS / 256; ++j) { local[j] = h[lo + j]; ls += local[j]; }
    partial[threadIdx.x] = ls;
    __syncthreads();
    for (int off = 1; off < 256; off <<= 1) {
        unsigned v = (threadIdx.x >= (unsigned)off) ? partial[threadIdx.x - off] : 0u;
        __syncthreads();
        partial[threadIdx.x] += v;
        __syncthreads();
    }
    unsigned run = partial[threadIdx.x] - ls;  // exclusive prefix

#pragma unroll
    for (int j = 0; j < NBINS / 256; ++j) {
        unsigned c = local[j];
        if (c) {
            if (run < r1 && run + c >= r1) { bi[0] = lo + j; bi[2] = run; }
            if (run < r2 && run + c >= r2) { bi[1] = lo + j; }
        }
        run += c;
    }
    (void)k;
}

// ---------------- pass 3: compact candidate values ----------------
__global__ __launch_bounds__(TPB) void k_compact(const float* __restrict__ pred,
                                                 const float* __restrict__ targ,
                                                 int nvec,
                                                 const unsigned* __restrict__ binfo,
                                                 unsigned* __restrict__ ccount,
                                                 float* __restrict__ cbuf)
{
    const int b = blockIdx.y;
    const unsigned lo_t = binfo[(2 * b + 0) * 8 + 0];
    const unsigned hi_t = binfo[(2 * b + 0) * 8 + 1];
    const unsigned lo_p = binfo[(2 * b + 1) * 8 + 0];
    const unsigned hi_p = binfo[(2 * b + 1) * 8 + 1];

    const float4* p4 = (const float4*)pred + (size_t)b * nvec;
    const float4* t4 = (const float4*)targ + (size_t)b * nvec;

    for (int i = blockIdx.x * blockDim.x + threadIdx.x; i < nvec;
         i += gridDim.x * blockDim.x) {
        float4 t = t4[i];
        float4 p = p4[i];
        float tv[4] = {t.x, t.y, t.z, t.w};
        float pv[4] = {p.x, p.y, p.z, p.w};
#pragma unroll
        for (int j = 0; j < 4; ++j) {
            float tt = tv[j], pp = pv[j];
            if (tt > 0.01f) {
                unsigned bt = (unsigned)bucketOf(tt);
                if (bt >= lo_t && bt <= hi_t) {
                    unsigned idx = atomicAdd(&ccount[2 * b + 0], 1u);
                    if (idx < CAP) cbuf[(size_t)(2 * b + 0) * CAP + idx] = tt;
                }
                if (pp > 0.f) {
                    unsigned bp = (unsigned)bucketOf(pp);
                    if (bp >= lo_p && bp <= hi_p) {
                        unsigned idx = atomicAdd(&ccount[2 * b + 1], 1u);
                        if (idx < CAP) cbuf[(size_t)(2 * b + 1) * CAP + idx] = pp;
                    }
                }
            }
        }
    }
}

// ---------------- pass 4: sort candidates, pick exact order stats ----------------
__global__ __launch_bounds__(1024) void k_sortsel(const unsigned* __restrict__ binfo,
                                                  const unsigned* __restrict__ ccount,
                                                  const float* __restrict__ cbuf,
                                                  float* __restrict__ thr)
{
    __shared__ float s[CAP];
    const int bt = blockIdx.x;
    const unsigned* bi = binfo + bt * 8;
    const unsigned nv = bi[5];
    if (nv == 0) {
        if (threadIdx.x == 0) thr[bt] = 0.01f;  // MASK_THRESHOLD fallback
        return;
    }
    unsigned n = ccount[bt];
    if (n > CAP) n = CAP;

    unsigned sn = 1;
    while (sn < n) sn <<= 1;
    for (unsigned i = threadIdx.x; i < sn; i += blockDim.x)
        s[i] = (i < n) ? cbuf[(size_t)bt * CAP + i] : 3.402823466e+38f;
    __syncthreads();

    for (unsigned ksz = 2; ksz <= sn; ksz <<= 1) {
        for (unsigned j = ksz >> 1; j > 0; j >>= 1) {
            for (unsigned i = threadIdx.x; i < sn; i += blockDim.x) {
                unsigned ixj = i ^ j;
                if (ixj > i) {
                    float a = s[i], c = s[ixj];
                    bool up = ((i & ksz) == 0);
                    if ((a > c) == up) { s[i] = c; s[ixj] = a; }
                }
            }
            __syncthreads();
        }
    }

    if (threadIdx.x == 0) {
        unsigned k = bi[3], cb = bi[2];
        float frac = __uint_as_float(bi[4]);
        long idx = (long)k - (long)cb;
        if (idx < 0) idx = 0;
        if (idx >= (long)n) idx = (long)n - 1;
        float v0 = s[idx];
        float v1 = (idx + 1 < (long)n) ? s[idx + 1] : v0;
        thr[bt] = v0 + frac * (v1 - v0);
    }
}

// ---------------- pass 5: hot-set counting ----------------
__global__ __launch_bounds__(TPB) void k_dice(const float* __restrict__ pred,
                                              const float* __restrict__ targ,
                                              int nvec,
                                              const float* __restrict__ thr,
                                              unsigned* __restrict__ hot)
{
    const int b = blockIdx.y;
    const float th_t = thr[2 * b + 0];
    const float th_p = thr[2 * b + 1];

    const float4* p4 = (const float4*)pred + (size_t)b * nvec;
    const float4* t4 = (const float4*)targ + (size_t)b * nvec;

    unsigned ct = 0, cp = 0, ci = 0;
    for (int i = blockIdx.x * blockDim.x + threadIdx.x; i < nvec;
         i += gridDim.x * blockDim.x) {
        float4 t = t4[i];
        float4 p = p4[i];
        float tv[4] = {t.x, t.y, t.z, t.w};
        float pv[4] = {p.x, p.y, p.z, p.w};
#pragma unroll
        for (int j = 0; j < 4; ++j) {
            float tt = tv[j], pp = pv[j];
            bool m = (tt > 0.01f);
            bool ht = m && (tt > th_t);
            bool hp = m && (pp > th_p);
            ct += ht ? 1u : 0u;
            cp += hp ? 1u : 0u;
            ci += (ht && hp) ? 1u : 0u;
        }
    }
    for (int off = 32; off; off >>= 1) {
        ct += __shfl_down(ct, off);
        cp += __shfl_down(cp, off);
        ci += __shfl_down(ci, off);
    }
    if ((threadIdx.x & 63) == 0) {
        if (ct) atomicAdd(&hot[3 * b + 0], ct);
        if (cp) atomicAdd(&hot[3 * b + 1], cp);
        if (ci) atomicAdd(&hot[3 * b + 2], ci);
    }
}

// ---------------- pass 6: combine ----------------
__global__ void k_final(const double* __restrict__ sse,
                        const unsigned* __restrict__ nvalid,
                        const unsigned* __restrict__ hot,
                        float* __restrict__ out)
{
    if (threadIdx.x == 0 && blockIdx.x == 0) {
        double acc = 0.0;
        for (int b = 0; b < NB; ++b) {
            double nv  = (double)nvalid[2 * b + 0];
            double mse = sse[b] / (nv + 1e-8);
            double T = (double)hot[3 * b + 0];
            double P = (double)hot[3 * b + 1];
            double I = (double)hot[3 * b + 2];
            double dice = 1.0 - 2.0 * I / (P + T + 1e-8);
            acc += 0.5 * mse + 0.5 * dice;
        }
        out[0] = (float)(acc / (double)NB);
    }
}

// ---------------- launcher ----------------
extern "C" void kernel_launch(void* const* d_in, const int* in_sizes, int n_in,
                              void* d_out, int out_size, void* d_ws, size_t ws_size,
                              hipStream_t stream) {
    const float* pred = (const float*)d_in[0];
    const float* targ = (const float*)d_in[1];
    float* out = (float*)d_out;

    const int total = in_sizes[0];
    const int N     = total / NB;      // 2,097,152
    const int nvec  = N / 4;

    // workspace layout (bytes)
    char* ws = (char*)d_ws;
    unsigned* hist   = (unsigned*)(ws + 0);        // 8*2*4096*4 = 262144
    double*   sse    = (double*)  (ws + 262144);   // 64
    unsigned* nvalid = (unsigned*)(ws + 262208);   // 64
    unsigned* hot    = (unsigned*)(ws + 262272);   // 96 (pad to 262400)
    unsigned* ccount = (unsigned*)(ws + 262400);   // 64
    unsigned* binfo  = (unsigned*)(ws + 262464);   // 512
    float*    thr    = (float*)   (ws + 262976);   // 64
    float*    cbuf   = (float*)   (ws + 263168);   // 8*2*16384*4 = 1048576
    (void)ws_size; (void)n_in; (void)out_size;

    hipMemsetAsync(ws, 0, 262464, stream);  // zero hist/sse/nvalid/hot/ccount

    dim3 gs(BPB, NB);
    k_pass1  <<<gs, TPB, 0, stream>>>(pred, targ, nvec, hist, sse, nvalid);
    k_scan   <<<2 * NB, 256, 0, stream>>>(hist, nvalid, binfo);
    k_compact<<<gs, TPB, 0, stream>>>(pred, targ, nvec, binfo, ccount, cbuf);
    k_sortsel<<<2 * NB, 1024, 0, stream>>>(binfo, ccount, cbuf, thr);
    k_dice   <<<gs, TPB, 0, stream>>>(pred, targ, nvec, thr, hot);
    k_final  <<<1, 64, 0, stream>>>(sse, nvalid, hot, out);
}